// Round 6
// baseline (33.278 us; speedup 1.0000x reference)
//
#include <hip/hip_runtime.h>

// y_pred: [B, PRED] fp32, y_ori: [B, T] fp32, SCALE = PRED/T = 4
#define B_ROWS   4096
#define T_LEN    2048
#define PRED_LEN 8192
#define NT       256
#define ITERS    (T_LEN / NT)   // 8 windows per thread

typedef float f32x4 __attribute__((ext_vector_type(4)));   // nt-load-compatible
typedef __attribute__((address_space(3))) void       lds_void_t;
typedef __attribute__((address_space(1))) const void gbl_void_t;

// Kernel 1: per-row masked MSE over detected maxima. One block per row.
// y_ori staged to LDS via global_load_lds; y_pred streamed into registers
// with non-temporal loads (single-pass stream, no reuse -> bypass cache).
__global__ __launch_bounds__(NT) void tsmal_row_kernel(
    const float* __restrict__ y_pred,
    const float* __restrict__ y_ori,
    float2* __restrict__ ws_res)    // [B] (loss, valid)
{
    __shared__ float s_ori[T_LEN];
    const int row  = blockIdx.x;
    const int tid  = threadIdx.x;
    const int wave = tid >> 6;
    const int lane = tid & 63;

    // 1) Async-stage y_ori row into LDS: 2 x 16B per thread.
    const float4* ori4   = reinterpret_cast<const float4*>(y_ori + (size_t)row * T_LEN);
    float4*       s_ori4 = reinterpret_cast<float4*>(s_ori);
    #pragma unroll
    for (int j = 0; j < T_LEN / 4 / NT; ++j) {
        const float4* gsrc = ori4 + (NT * j + tid);          // per-lane global src
        float4*       ldst = s_ori4 + (NT * j + wave * 64);  // wave-uniform base
        __builtin_amdgcn_global_load_lds((gbl_void_t*)gsrc, (lds_void_t*)ldst, 16, 0, 0);
    }

    // 2) Issue ALL y_pred loads (8 x 16B per thread, coalesced, non-temporal).
    const f32x4* pred4 = reinterpret_cast<const f32x4*>(y_pred + (size_t)row * PRED_LEN);
    f32x4 p[ITERS];
    #pragma unroll
    for (int k = 0; k < ITERS; ++k)
        p[k] = __builtin_nontemporal_load(pred4 + tid + NT * k);

    __syncthreads();   // drains vmcnt (pred + lds-stage) and publishes s_ori

    // 3) Masked squared error per window.
    float sum = 0.0f;
    float cnt = 0.0f;
    #pragma unroll
    for (int k = 0; k < ITERS; ++k) {
        const int i = tid + NT * k;
        float wm = fmaxf(fmaxf(p[k][0], p[k][1]), fmaxf(p[k][2], p[k][3]));

        int im1 = (i >= 1) ? i - 1 : 0;
        int ip1 = (i <= T_LEN - 2) ? i + 1 : T_LEN - 1;
        float yc = s_ori[i];
        float dm = yc - s_ori[im1];           // diff[i-1]
        float dp = s_ori[ip1] - yc;           // diff[i]
        bool interior = (i >= 1) && (i <= T_LEN - 2);
        bool mask = interior && (dp * dm < 0.0f) && (dm > 0.0f);

        float d = wm - yc;
        sum += mask ? d * d : 0.0f;
        cnt += mask ? 1.0f : 0.0f;
    }

    // 4) Wave + cross-wave reduction.
    #pragma unroll
    for (int off = 32; off > 0; off >>= 1) {
        sum += __shfl_down(sum, off, 64);
        cnt += __shfl_down(cnt, off, 64);
    }
    __shared__ float s_sum[NT / 64];
    __shared__ float s_cnt[NT / 64];
    if (lane == 0) { s_sum[wave] = sum; s_cnt[wave] = cnt; }
    __syncthreads();

    if (tid == 0) {
        float tsum = 0.0f, tcnt = 0.0f;
        #pragma unroll
        for (int w = 0; w < NT / 64; ++w) { tsum += s_sum[w]; tcnt += s_cnt[w]; }
        bool valid = tcnt > 0.0f;
        ws_res[row] = make_float2(valid ? tsum / tcnt : 0.0f, valid ? 1.0f : 0.0f);
    }
}

// Kernel 2: reduce per-row (loss, valid) pairs to the final scalar.
#define NT2 1024
__global__ __launch_bounds__(NT2) void tsmal_final_kernel(
    const float2* __restrict__ ws_res,
    float* __restrict__ out)
{
    const int tid = threadIdx.x;
    // 4096 float2 = 2048 float4; 1024 threads -> 2 float4 each.
    const float4* r4 = reinterpret_cast<const float4*>(ws_res);
    float total = 0.0f, nvalid = 0.0f;
    #pragma unroll
    for (int j = 0; j < 2; ++j) {
        float4 a = r4[tid + NT2 * j];
        total  += a.x + a.z;   // loss components
        nvalid += a.y + a.w;   // valid components
    }
    #pragma unroll
    for (int off = 32; off > 0; off >>= 1) {
        total  += __shfl_down(total, off, 64);
        nvalid += __shfl_down(nvalid, off, 64);
    }
    __shared__ float s_tot[NT2 / 64];
    __shared__ float s_nv[NT2 / 64];
    const int wave = tid >> 6;
    const int lane = tid & 63;
    if (lane == 0) { s_tot[wave] = total; s_nv[wave] = nvalid; }
    __syncthreads();
    if (tid == 0) {
        float t = 0.0f, nv = 0.0f;
        #pragma unroll
        for (int w = 0; w < NT2 / 64; ++w) { t += s_tot[w]; nv += s_nv[w]; }
        out[0] = (nv > 0.0f) ? t / nv : 0.0f;
    }
}

extern "C" void kernel_launch(void* const* d_in, const int* in_sizes, int n_in,
                              void* d_out, int out_size, void* d_ws, size_t ws_size,
                              hipStream_t stream) {
    const float* y_pred = (const float*)d_in[0];
    const float* y_ori  = (const float*)d_in[1];
    float* out = (float*)d_out;

    float2* ws_res = (float2*)d_ws;   // [B_ROWS] (loss, valid)

    tsmal_row_kernel<<<B_ROWS, NT, 0, stream>>>(y_pred, y_ori, ws_res);
    tsmal_final_kernel<<<1, NT2, 0, stream>>>(ws_res, out);
}

// Round 7
// 32.616 us; speedup vs baseline: 1.0203x; 1.0203x over previous
//
#include <hip/hip_runtime.h>

// y_pred: [B, PRED] fp32, y_ori: [B, T] fp32, SCALE = PRED/T = 4
#define B_ROWS   4096
#define T_LEN    2048
#define PRED_LEN 8192
#define NT       256
#define RPB      2                              // rows per block
#define NBLK     (B_ROWS / RPB)                 // 2048 blocks
#define ITERS    (RPB * T_LEN / NT)             // 16 windows per thread
#define HALF     (ITERS / 2)                    // 8 -> first row's windows

typedef __attribute__((address_space(3))) void       lds_void_t;
typedef __attribute__((address_space(1))) const void gbl_void_t;

// Kernel 1: two adjacent rows per block (contiguous in memory -> one long
// stream). y_ori rows staged to LDS via global_load_lds; y_pred streamed
// into registers. Block writes one combined (loss_sum, valid_count) pair.
__global__ __launch_bounds__(NT) void tsmal_row_kernel(
    const float* __restrict__ y_pred,
    const float* __restrict__ y_ori,
    float2* __restrict__ ws_res)    // [NBLK] (loss_sum, valid_count)
{
    __shared__ float s_ori[RPB * T_LEN];        // 16 KB: both rows concatenated
    const int row0 = blockIdx.x * RPB;
    const int tid  = threadIdx.x;
    const int wave = tid >> 6;
    const int lane = tid & 63;

    // 1) Async-stage both y_ori rows (4096 contiguous floats, 4 x 16B/thread).
    const float4* ori4   = reinterpret_cast<const float4*>(y_ori + (size_t)row0 * T_LEN);
    float4*       s_ori4 = reinterpret_cast<float4*>(s_ori);
    #pragma unroll
    for (int j = 0; j < RPB * T_LEN / 4 / NT; ++j) {
        const float4* gsrc = ori4 + (NT * j + tid);          // per-lane global src
        float4*       ldst = s_ori4 + (NT * j + wave * 64);  // wave-uniform base
        __builtin_amdgcn_global_load_lds((gbl_void_t*)gsrc, (lds_void_t*)ldst, 16, 0, 0);
    }

    // 2) Issue ALL y_pred loads (16 x float4 per thread, contiguous 64 KB).
    const float4* pred4 = reinterpret_cast<const float4*>(y_pred + (size_t)row0 * PRED_LEN);
    float4 p[ITERS];
    #pragma unroll
    for (int k = 0; k < ITERS; ++k)
        p[k] = pred4[tid + NT * k];

    __syncthreads();   // drains vmcnt (pred + lds-stage) and publishes s_ori

    // 3) Masked squared error per window; separate accumulators per row.
    float sumA = 0.0f, cntA = 0.0f, sumB = 0.0f, cntB = 0.0f;
    #pragma unroll
    for (int k = 0; k < ITERS; ++k) {
        const int ig = tid + NT * k;            // 0..4095 over both rows
        const int il = ig & (T_LEN - 1);        // index within its row
        float wm = fmaxf(fmaxf(p[k].x, p[k].y), fmaxf(p[k].z, p[k].w));

        bool interior = (il >= 1) && (il <= T_LEN - 2);
        int im1 = interior ? ig - 1 : ig;
        int ip1 = interior ? ig + 1 : ig;
        float yc = s_ori[ig];
        float dm = yc - s_ori[im1];             // diff[il-1]
        float dp = s_ori[ip1] - yc;             // diff[il]
        bool mask = interior && (dp * dm < 0.0f) && (dm > 0.0f);

        float d  = wm - yc;
        float sq = mask ? d * d : 0.0f;
        float c  = mask ? 1.0f : 0.0f;
        if (k < HALF) { sumA += sq; cntA += c; }
        else          { sumB += sq; cntB += c; }
    }

    // 4) Wave + cross-wave reduction of 4 partials.
    #pragma unroll
    for (int off = 32; off > 0; off >>= 1) {
        sumA += __shfl_down(sumA, off, 64);
        cntA += __shfl_down(cntA, off, 64);
        sumB += __shfl_down(sumB, off, 64);
        cntB += __shfl_down(cntB, off, 64);
    }
    __shared__ float s_red[4][NT / 64];
    if (lane == 0) {
        s_red[0][wave] = sumA; s_red[1][wave] = cntA;
        s_red[2][wave] = sumB; s_red[3][wave] = cntB;
    }
    __syncthreads();

    if (tid == 0) {
        float tsA = 0.0f, tcA = 0.0f, tsB = 0.0f, tcB = 0.0f;
        #pragma unroll
        for (int w = 0; w < NT / 64; ++w) {
            tsA += s_red[0][w]; tcA += s_red[1][w];
            tsB += s_red[2][w]; tcB += s_red[3][w];
        }
        float loss = 0.0f, nval = 0.0f;
        if (tcA > 0.0f) { loss += tsA / tcA; nval += 1.0f; }
        if (tcB > 0.0f) { loss += tsB / tcB; nval += 1.0f; }
        ws_res[blockIdx.x] = make_float2(loss, nval);
    }
}

// Kernel 2: reduce per-block (loss_sum, valid_count) pairs to final scalar.
#define NT2 1024
__global__ __launch_bounds__(NT2) void tsmal_final_kernel(
    const float2* __restrict__ ws_res,
    float* __restrict__ out)
{
    const int tid = threadIdx.x;
    // 2048 float2 = 1024 float4; one float4 per thread.
    const float4* r4 = reinterpret_cast<const float4*>(ws_res);
    float4 a = r4[tid];
    float total  = a.x + a.z;
    float nvalid = a.y + a.w;
    #pragma unroll
    for (int off = 32; off > 0; off >>= 1) {
        total  += __shfl_down(total, off, 64);
        nvalid += __shfl_down(nvalid, off, 64);
    }
    __shared__ float s_tot[NT2 / 64];
    __shared__ float s_nv[NT2 / 64];
    const int wave = tid >> 6;
    const int lane = tid & 63;
    if (lane == 0) { s_tot[wave] = total; s_nv[wave] = nvalid; }
    __syncthreads();
    if (tid == 0) {
        float t = 0.0f, nv = 0.0f;
        #pragma unroll
        for (int w = 0; w < NT2 / 64; ++w) { t += s_tot[w]; nv += s_nv[w]; }
        out[0] = (nv > 0.0f) ? t / nv : 0.0f;
    }
}

extern "C" void kernel_launch(void* const* d_in, const int* in_sizes, int n_in,
                              void* d_out, int out_size, void* d_ws, size_t ws_size,
                              hipStream_t stream) {
    const float* y_pred = (const float*)d_in[0];
    const float* y_ori  = (const float*)d_in[1];
    float* out = (float*)d_out;

    float2* ws_res = (float2*)d_ws;   // [NBLK] (loss_sum, valid_count)

    tsmal_row_kernel<<<NBLK, NT, 0, stream>>>(y_pred, y_ori, ws_res);
    tsmal_final_kernel<<<1, NT2, 0, stream>>>(ws_res, out);
}

// Round 8
// 32.147 us; speedup vs baseline: 1.0352x; 1.0146x over previous
//
#include <hip/hip_runtime.h>

// y_pred: [B, PRED] fp32, y_ori: [B, T] fp32, SCALE = PRED/T = 4
#define B_ROWS   4096
#define T_LEN    2048
#define PRED_LEN 8192
#define NT       256
#define ITERS    (T_LEN / NT)   // 8 windows per thread

typedef __attribute__((address_space(3))) void       lds_void_t;
typedef __attribute__((address_space(1))) const void gbl_void_t;

// Kernel 1: per-row masked MSE over detected maxima. One block per row.
// y_ori staged to LDS via global_load_lds (no VGPR round-trip); y_pred
// streams straight into registers. All 10 VMEM ops per thread are in flight
// before the single barrier. Best-measured structure (31.92 us, R4).
__global__ __launch_bounds__(NT) void tsmal_row_kernel(
    const float* __restrict__ y_pred,
    const float* __restrict__ y_ori,
    float2* __restrict__ ws_res)    // [B] (loss, valid)
{
    __shared__ float s_ori[T_LEN];
    const int row  = blockIdx.x;
    const int tid  = threadIdx.x;
    const int wave = tid >> 6;
    const int lane = tid & 63;

    // 1) Async-stage y_ori row into LDS: 2 x 16B per thread.
    const float4* ori4   = reinterpret_cast<const float4*>(y_ori + (size_t)row * T_LEN);
    float4*       s_ori4 = reinterpret_cast<float4*>(s_ori);
    #pragma unroll
    for (int j = 0; j < T_LEN / 4 / NT; ++j) {
        const float4* gsrc = ori4 + (NT * j + tid);          // per-lane global src
        float4*       ldst = s_ori4 + (NT * j + wave * 64);  // wave-uniform base
        __builtin_amdgcn_global_load_lds((gbl_void_t*)gsrc, (lds_void_t*)ldst, 16, 0, 0);
    }

    // 2) Issue ALL y_pred loads (8 x float4 per thread, coalesced).
    const float4* pred4 = reinterpret_cast<const float4*>(y_pred + (size_t)row * PRED_LEN);
    float4 p[ITERS];
    #pragma unroll
    for (int k = 0; k < ITERS; ++k)
        p[k] = pred4[tid + NT * k];

    __syncthreads();   // drains vmcnt (pred + lds-stage) and publishes s_ori

    // 3) Masked squared error per window.
    float sum = 0.0f;
    float cnt = 0.0f;
    #pragma unroll
    for (int k = 0; k < ITERS; ++k) {
        const int i = tid + NT * k;
        float wm = fmaxf(fmaxf(p[k].x, p[k].y), fmaxf(p[k].z, p[k].w));

        int im1 = (i >= 1) ? i - 1 : 0;
        int ip1 = (i <= T_LEN - 2) ? i + 1 : T_LEN - 1;
        float yc = s_ori[i];
        float dm = yc - s_ori[im1];           // diff[i-1]
        float dp = s_ori[ip1] - yc;           // diff[i]
        bool interior = (i >= 1) && (i <= T_LEN - 2);
        bool mask = interior && (dp * dm < 0.0f) && (dm > 0.0f);

        float d = wm - yc;
        sum += mask ? d * d : 0.0f;
        cnt += mask ? 1.0f : 0.0f;
    }

    // 4) Wave + cross-wave reduction.
    #pragma unroll
    for (int off = 32; off > 0; off >>= 1) {
        sum += __shfl_down(sum, off, 64);
        cnt += __shfl_down(cnt, off, 64);
    }
    __shared__ float s_sum[NT / 64];
    __shared__ float s_cnt[NT / 64];
    if (lane == 0) { s_sum[wave] = sum; s_cnt[wave] = cnt; }
    __syncthreads();

    if (tid == 0) {
        float tsum = 0.0f, tcnt = 0.0f;
        #pragma unroll
        for (int w = 0; w < NT / 64; ++w) { tsum += s_sum[w]; tcnt += s_cnt[w]; }
        bool valid = tcnt > 0.0f;
        ws_res[row] = make_float2(valid ? tsum / tcnt : 0.0f, valid ? 1.0f : 0.0f);
    }
}

// Kernel 2: reduce per-row (loss, valid) pairs to the final scalar.
#define NT2 1024
__global__ __launch_bounds__(NT2) void tsmal_final_kernel(
    const float2* __restrict__ ws_res,
    float* __restrict__ out)
{
    const int tid = threadIdx.x;
    // 4096 float2 = 2048 float4; 1024 threads -> 2 float4 each.
    const float4* r4 = reinterpret_cast<const float4*>(ws_res);
    float total = 0.0f, nvalid = 0.0f;
    #pragma unroll
    for (int j = 0; j < 2; ++j) {
        float4 a = r4[tid + NT2 * j];
        total  += a.x + a.z;   // loss components
        nvalid += a.y + a.w;   // valid components
    }
    #pragma unroll
    for (int off = 32; off > 0; off >>= 1) {
        total  += __shfl_down(total, off, 64);
        nvalid += __shfl_down(nvalid, off, 64);
    }
    __shared__ float s_tot[NT2 / 64];
    __shared__ float s_nv[NT2 / 64];
    const int wave = tid >> 6;
    const int lane = tid & 63;
    if (lane == 0) { s_tot[wave] = total; s_nv[wave] = nvalid; }
    __syncthreads();
    if (tid == 0) {
        float t = 0.0f, nv = 0.0f;
        #pragma unroll
        for (int w = 0; w < NT2 / 64; ++w) { t += s_tot[w]; nv += s_nv[w]; }
        out[0] = (nv > 0.0f) ? t / nv : 0.0f;
    }
}

extern "C" void kernel_launch(void* const* d_in, const int* in_sizes, int n_in,
                              void* d_out, int out_size, void* d_ws, size_t ws_size,
                              hipStream_t stream) {
    const float* y_pred = (const float*)d_in[0];
    const float* y_ori  = (const float*)d_in[1];
    float* out = (float*)d_out;

    float2* ws_res = (float2*)d_ws;   // [B_ROWS] (loss, valid)

    tsmal_row_kernel<<<B_ROWS, NT, 0, stream>>>(y_pred, y_ori, ws_res);
    tsmal_final_kernel<<<1, NT2, 0, stream>>>(ws_res, out);
}